// Round 2
// baseline (8941.634 us; speedup 1.0000x reference)
//
#include <hip/hip_runtime.h>

// np.float32(np.pi / 180)
#define PI180F 0.017453292519943295f

// ---------------------------------------------------------------------------
// Rotation matrix, matching the reference's (Rz @ Ry) @ Rx in fp32.
// ---------------------------------------------------------------------------
__device__ __forceinline__ void compute_R(const float th[6], float R[9], float t[3]) {
    float ax = th[0] * PI180F, ay = th[1] * PI180F, az = th[2] * PI180F;
    float cx = cosf(ax), sx = sinf(ax);
    float cy = cosf(ay), sy = sinf(ay);
    float cz = cosf(az), sz = sinf(az);
    R[0] = cz * cy;  R[1] = (cz * sy) * sx - sz * cx;  R[2] = (cz * sy) * cx + sz * sx;
    R[3] = sz * cy;  R[4] = (sz * sy) * sx + cz * cx;  R[5] = (sz * sy) * cx - cz * sx;
    R[6] = -sy;      R[7] = cy * sx;                   R[8] = cy * cx;
    t[0] = th[3]; t[1] = th[4]; t[2] = th[5];
}

// ---------------------------------------------------------------------------
// Trilinear sample matching jax.scipy.ndimage.map_coordinates(order=1,
// mode='constant', cval=0). Interior fast path: one base pointer + 8
// constant-offset loads. Accumulation expression identical in both paths.
// ---------------------------------------------------------------------------
__device__ __forceinline__ float tri_sample(const float* __restrict__ vol, int D, int logD,
                                            float c0, float c1, float c2) {
    float f0 = floorf(c0), f1 = floorf(c1), f2 = floorf(c2);
    int i0 = (int)f0, i1 = (int)f1, i2 = (int)f2;
    float t0 = c0 - f0, t1 = c1 - f1, t2 = c2 - f2;
    float u0 = 1.0f - t0, u1 = 1.0f - t1, u2 = 1.0f - t2;
    float v000, v001, v010, v011, v100, v101, v110, v111;
    // all 8 corners in-bounds iff 0 <= i < D-1 per axis
    if (((unsigned)i0 < (unsigned)(D - 1)) &
        ((unsigned)i1 < (unsigned)(D - 1)) &
        ((unsigned)i2 < (unsigned)(D - 1))) {
        const float* p = vol + ((((i0 << logD) + i1) << logD) + i2);
        const int DD = D * D;
        v000 = p[0];      v001 = p[1];
        v010 = p[D];      v011 = p[D + 1];
        v100 = p[DD];     v101 = p[DD + 1];
        v110 = p[DD + D]; v111 = p[DD + D + 1];
    } else {
        // rare boundary path; loads predicated by validity (no OOB access)
        float vals[8];
#pragma unroll
        for (int a = 0; a < 2; ++a) {
            int ia = i0 + a;
            bool va = (unsigned)ia < (unsigned)D;
#pragma unroll
            for (int b = 0; b < 2; ++b) {
                int ib = i1 + b;
                bool vb = (unsigned)ib < (unsigned)D;
#pragma unroll
                for (int c = 0; c < 2; ++c) {
                    int ic = i2 + c;
                    bool vc = (unsigned)ic < (unsigned)D;
                    vals[a * 4 + b * 2 + c] =
                        (va && vb && vc) ? vol[(ia * D + ib) * D + ic] : 0.0f;
                }
            }
        }
        v000 = vals[0]; v001 = vals[1]; v010 = vals[2]; v011 = vals[3];
        v100 = vals[4]; v101 = vals[5]; v110 = vals[6]; v111 = vals[7];
    }
    float w00 = u0 * u1, w01 = u0 * t1, w10 = t0 * u1, w11 = t0 * t1;
    float acc = (w00 * u2) * v000;
    acc += (w00 * t2) * v001;
    acc += (w01 * u2) * v010;
    acc += (w01 * t2) * v011;
    acc += (w10 * u2) * v100;
    acc += (w10 * t2) * v101;
    acc += (w11 * u2) * v110;
    acc += (w11 * t2) * v111;
    return acc;
}

// ---------------------------------------------------------------------------
// Shared eval body: partial SSE for one (config, row, chunk).
// ---------------------------------------------------------------------------
__device__ __forceinline__ void eval_body(
    const float* __restrict__ src, const float* __restrict__ tgt,
    const float th[6], int b, int k, int K, int D, int logD,
    double* __restrict__ red /*[256]*/, double* __restrict__ partial_slot)
{
    float R[9], t[3];
    compute_R(th, R, t);
    const int n = D * D * D;
    const float step = 2.0f / (float)(D - 1);
    const float scale = (float)(D - 1) * 0.5f;
    const int chunk = n / K;
    const int v0 = k * chunk;
    const float* s = src + (size_t)b * n;
    const float* g = tgt + (size_t)b * n;
    const int tid = threadIdx.x;

    double acc = 0.0;
    for (int v = v0 + tid; v < v0 + chunk; v += 256) {
        int kk = v & (D - 1);
        int jj = (v >> logD) & (D - 1);
        int ii = v >> (2 * logD);
        float x0 = -1.0f + (float)ii * step;
        float x1 = -1.0f + (float)jj * step;
        float x2 = -1.0f + (float)kk * step;
        float p0 = R[0] * x0 + R[1] * x1 + R[2] * x2 + t[0];
        float p1 = R[3] * x0 + R[4] * x1 + R[5] * x2 + t[1];
        float p2 = R[6] * x0 + R[7] * x1 + R[8] * x2 + t[2];
        float w = tri_sample(s, D, logD,
                             (p0 + 1.0f) * scale, (p1 + 1.0f) * scale, (p2 + 1.0f) * scale);
        float d = w - g[v];
        acc += (double)(d * d);
    }
    red[tid] = acc;
    __syncthreads();
#pragma unroll
    for (int st = 128; st > 0; st >>= 1) {
        if (tid < st) red[tid] += red[tid + st];
        __syncthreads();
    }
    if (tid == 0) *partial_slot = red[0];
}

// ---------------------------------------------------------------------------
// FD eval + fused update1 tail (last-block pattern).
// first=1: 13 configs (c=0..12), also initializes loss_cur; momentum off.
// first=0: 12 configs (c=1..12), base loss from loss_cur; momentum on.
// ---------------------------------------------------------------------------
__global__ __launch_bounds__(256) void eval_fd_kernel(
    const float* __restrict__ src, const float* __restrict__ tgt,
    const float* __restrict__ theta,
    float* __restrict__ theta_try, float* __restrict__ momentum,
    float* __restrict__ loss_cur, float* __restrict__ loss_all,
    const int* __restrict__ active,
    double* __restrict__ partials, int* __restrict__ counter,
    int D, int logD, int K, float ss, int first)
{
    __shared__ double red[256];
    __shared__ float lossf[104];
    __shared__ int lastf;
    const int tid = threadIdx.x;
    const int gb = blockIdx.x;
    const int k = gb % K;
    const int e = gb / K;
    const int b = e & 7;
    const int c = first ? (e >> 3) : (e >> 3) + 1;
    const int n = D * D * D;

    if (active[b]) {
        float th[6];
#pragma unroll
        for (int j = 0; j < 6; ++j) th[j] = theta[b * 6 + j];
        if (c > 0) {
            int j = (c - 1) % 6;
            th[j] += (c <= 6) ? ss : -ss;
        }
        eval_body(src, tgt, th, b, k, K, D, logD, red,
                  &partials[(size_t)(c * 8 + b) * K + k]);
    }

    __threadfence();
    if (tid == 0) lastf = (atomicAdd(counter, 1) == (int)gridDim.x - 1) ? 1 : 0;
    __syncthreads();
    if (!lastf) return;

    // ---- elected last block: update1 ----
    if (tid == 0) *counter = 0;
    __threadfence();
    const int nc = first ? 13 : 12;
    if (tid < nc * 8) {
        int cc = first ? (tid >> 3) : (tid >> 3) + 1;
        int bb = tid & 7;
        double s = 0.0;
#pragma unroll 4
        for (int i = 0; i < K; ++i) s += partials[(size_t)(cc * 8 + bb) * K + i];
        lossf[cc * 8 + bb] = (float)(s / (double)n);
    }
    __syncthreads();
    if (tid < 8 && active[tid]) {
        int bb = tid;
        float lb = first ? lossf[bb] : loss_cur[bb];
        loss_cur[bb] = lb;
        loss_all[bb] = lb;
        float ub[6];
#pragma unroll
        for (int j = 0; j < 6; ++j) {
            float grad = lossf[(1 + j) * 8 + bb] - lossf[(7 + j) * 8 + bb];
            float u = first ? grad : (momentum[bb * 6 + j] * 0.1f + grad);
            momentum[bb * 6 + j] = u;
            ub[j] = u;
        }
        float ss2 = 0.0f;
#pragma unroll
        for (int j = 0; j < 6; ++j) ss2 += ub[j] * ub[j];
        float denom = sqrtf(ss2) + 1e-6f;
#pragma unroll
        for (int j = 0; j < 6; ++j) {
            float d = ub[j] / denom;
            theta_try[bb * 6 + j] = theta[bb * 6 + j] - ss * d;
        }
    }
}

// ---------------------------------------------------------------------------
// Trial eval + fused update2 tail. reset_active=1 on the last iteration of a
// step (prepares the next step).
// ---------------------------------------------------------------------------
__global__ __launch_bounds__(256) void eval_trial_kernel(
    const float* __restrict__ src, const float* __restrict__ tgt,
    const float* __restrict__ theta_try,
    float* __restrict__ theta, float* __restrict__ loss_cur,
    int* __restrict__ active,
    double* __restrict__ partials, int* __restrict__ counter,
    int D, int logD, int K, int reset_active)
{
    __shared__ double red[256];
    __shared__ int lastf;
    const int tid = threadIdx.x;
    const int gb = blockIdx.x;
    const int k = gb % K;
    const int b = gb / K;
    const int n = D * D * D;

    if (active[b]) {
        float th[6];
#pragma unroll
        for (int j = 0; j < 6; ++j) th[j] = theta_try[b * 6 + j];
        eval_body(src, tgt, th, b, k, K, D, logD, red,
                  &partials[(size_t)b * K + k]);
    }

    __threadfence();
    if (tid == 0) lastf = (atomicAdd(counter, 1) == (int)gridDim.x - 1) ? 1 : 0;
    __syncthreads();
    if (!lastf) return;

    // ---- elected last block: update2 ----
    if (tid == 0) *counter = 0;
    __threadfence();
    if (tid < 8) {
        int bb = tid;
        if (active[bb]) {
            double s = 0.0;
#pragma unroll 4
            for (int i = 0; i < K; ++i) s += partials[(size_t)bb * K + i];
            float ln = (float)(s / (double)n);
            if (ln + 1e-4f < loss_cur[bb]) {
#pragma unroll
                for (int j = 0; j < 6; ++j) theta[bb * 6 + j] = theta_try[bb * 6 + j];
                loss_cur[bb] = ln;
            } else {
                active[bb] = 0;
            }
        }
        if (reset_active) active[bb] = 1;
    }
}

// ---------------------------------------------------------------------------
// Pool both src and tgt in one kernel: mean over f^3 blocks (input D=64).
// ---------------------------------------------------------------------------
__global__ void pool_kernel(const float* __restrict__ a, const float* __restrict__ bsrc,
                            float* __restrict__ oa, float* __restrict__ ob, int f)
{
    int Do = 64 / f;
    int n = 8 * Do * Do * Do;
    int idx = blockIdx.x * blockDim.x + threadIdx.x;
    if (idx >= 2 * n) return;
    const float* in = (idx < n) ? a : bsrc;
    float* out = (idx < n) ? oa : ob;
    int id = (idx < n) ? idx : idx - n;
    int kk = id % Do;
    int jj = (id / Do) % Do;
    int ii = (id / (Do * Do)) % Do;
    int bq = id / (Do * Do * Do);
    const float* v = in + (size_t)bq * 64 * 64 * 64;
    double s = 0.0;
    for (int p = 0; p < f; ++p)
        for (int q = 0; q < f; ++q)
            for (int r = 0; r < f; ++r)
                s += (double)v[((ii * f + p) * 64 + (jj * f + q)) * 64 + (kk * f + r)];
    out[id] = (float)(s / (double)(f * f * f));
}

__global__ void init_kernel(const float* __restrict__ theta_in,
                            float* __restrict__ theta_deg,
                            int* __restrict__ active,
                            int* __restrict__ counters)
{
    int t = threadIdx.x;
    if (t < 48) {
        int j = t % 6;
        float d2r = (j < 3) ? PI180F : 1.0f;
        theta_deg[t] = theta_in[t] / d2r;
    }
    if (t < 8) active[t] = 1;
    if (t < 2) counters[t] = 0;
}

__global__ void finalize_kernel(const float* __restrict__ theta0,
                                const float* __restrict__ theta_deg,
                                const float* __restrict__ loss_all,
                                float* __restrict__ out)
{
    int t = threadIdx.x;
    if (t < 48) {
        int j = t % 6;
        float d2r = (j < 3) ? PI180F : 1.0f;
        float td = theta_deg[t] * d2r;
        float dt = td - theta0[t];
        out[t] = theta0[t] + dt;
    } else if (t < 56) {
        out[t] = loss_all[t - 48];
    }
}

// ---------------------------------------------------------------------------
extern "C" void kernel_launch(void* const* d_in, const int* in_sizes, int n_in,
                              void* d_out, int out_size, void* d_ws, size_t ws_size,
                              hipStream_t stream)
{
    const float* theta0 = (const float*)d_in[0];
    const float* source = (const float*)d_in[1];
    const float* target = (const float*)d_in[2];
    float* out = (float*)d_out;

    char* ws = (char*)d_ws;
    size_t off = 0;
    auto alloc = [&](size_t bytes) -> void* {
        off = (off + 255) & ~(size_t)255;
        void* p = ws + off;
        off += bytes;
        return p;
    };
    float*  theta  = (float*)alloc(48 * 4);
    float*  ttry   = (float*)alloc(48 * 4);
    float*  mom    = (float*)alloc(48 * 4);
    float*  lcur   = (float*)alloc(8 * 4);
    float*  lall   = (float*)alloc(8 * 4);
    int*    active = (int*)alloc(8 * 4);
    int*    ctrs   = (int*)alloc(2 * 4);
    double* pA     = (double*)alloc(104 * 32 * 8);
    double* pB     = (double*)alloc(8 * 128 * 8);
    float*  src2   = (float*)alloc((size_t)8 * 32768 * 4);
    float*  tgt2   = (float*)alloc((size_t)8 * 32768 * 4);
    float*  src4   = (float*)alloc((size_t)8 * 4096 * 4);
    float*  tgt4   = (float*)alloc((size_t)8 * 4096 * 4);

    pool_kernel<<<(2 * 8 * 32768 + 255) / 256, 256, 0, stream>>>(source, target, src2, tgt2, 2);
    pool_kernel<<<(2 * 8 * 4096 + 255) / 256, 256, 0, stream>>>(source, target, src4, tgt4, 4);
    init_kernel<<<1, 64, 0, stream>>>(theta0, theta, active, ctrs);

    struct Lv { const float* s; const float* g; int D; int logD; int K; int K3; float ss0; };
    Lv lvs[3] = {
        { src4,   tgt4,   16, 4,  2,   8,  8.0f },
        { src2,   tgt2,   32, 5,  8,  32,  4.0f },
        { source, target, 64, 6, 16,  64,  2.0f },
    };

    for (int L = 0; L < 3; ++L) {
        Lv lv = lvs[L];
        float ssv = lv.ss0;
        for (int s = 0; s < 4; ++s) {
            for (int it = 0; it < 10; ++it) {
                int first = (s == 0 && it == 0) ? 1 : 0;
                int nconf = first ? 13 : 12;
                eval_fd_kernel<<<nconf * 8 * lv.K, 256, 0, stream>>>(
                    lv.s, lv.g, theta, ttry, mom, lcur, lall, active, pA, &ctrs[0],
                    lv.D, lv.logD, lv.K, ssv, first);
                int reset = (it == 9) ? 1 : 0;
                eval_trial_kernel<<<8 * lv.K3, 256, 0, stream>>>(
                    lv.s, lv.g, ttry, theta, lcur, active, pB, &ctrs[1],
                    lv.D, lv.logD, lv.K3, reset);
            }
            ssv *= 0.5f;
        }
    }

    finalize_kernel<<<1, 64, 0, stream>>>(theta0, theta, lall, out);
}

// Round 3
// 1530.997 us; speedup vs baseline: 5.8404x; 5.8404x over previous
//
#include <hip/hip_runtime.h>

// np.float32(np.pi / 180)
#define PI180F 0.017453292519943295f

// ---------------------------------------------------------------------------
// Rotation matrix, matching the reference's (Rz @ Ry) @ Rx in fp32.
// ---------------------------------------------------------------------------
__device__ __forceinline__ void compute_R(const float th[6], float R[9], float t[3]) {
    float ax = th[0] * PI180F, ay = th[1] * PI180F, az = th[2] * PI180F;
    float cx = cosf(ax), sx = sinf(ax);
    float cy = cosf(ay), sy = sinf(ay);
    float cz = cosf(az), sz = sinf(az);
    R[0] = cz * cy;  R[1] = (cz * sy) * sx - sz * cx;  R[2] = (cz * sy) * cx + sz * sx;
    R[3] = sz * cy;  R[4] = (sz * sy) * sx + cz * cx;  R[5] = (sz * sy) * cx - cz * sx;
    R[6] = -sy;      R[7] = cy * sx;                   R[8] = cy * cx;
    t[0] = th[3]; t[1] = th[4]; t[2] = th[5];
}

// ---------------------------------------------------------------------------
// Trilinear sample matching jax.scipy.ndimage.map_coordinates(order=1,
// mode='constant', cval=0): straight-line predicated form (round-1 proven).
// ---------------------------------------------------------------------------
__device__ __forceinline__ float tri_sample(const float* __restrict__ vol, int D,
                                             float c0, float c1, float c2) {
    float f0 = floorf(c0), f1 = floorf(c1), f2 = floorf(c2);
    int i0 = (int)f0, i1 = (int)f1, i2 = (int)f2;
    float t0 = c0 - f0, t1 = c1 - f1, t2 = c2 - f2;
    float w0[2] = {1.0f - t0, t0};
    float w1[2] = {1.0f - t1, t1};
    float w2[2] = {1.0f - t2, t2};
    float acc = 0.0f;
#pragma unroll
    for (int a = 0; a < 2; ++a) {
        int ia = i0 + a;
        bool va = (ia >= 0) && (ia < D);
#pragma unroll
        for (int b = 0; b < 2; ++b) {
            int ib = i1 + b;
            bool vb = (ib >= 0) && (ib < D);
#pragma unroll
            for (int c = 0; c < 2; ++c) {
                int ic = i2 + c;
                bool vc = (ic >= 0) && (ic < D);
                float val = (va && vb && vc) ? vol[(ia * D + ib) * D + ic] : 0.0f;
                acc += ((w0[a] * w1[b]) * w2[c]) * val;
            }
        }
    }
    return acc;
}

// ---------------------------------------------------------------------------
// Eval kernel (round-1 structure): partial SSE sums for warped(src) vs tgt.
// mode=0: trial (1 config, theta ptr = theta_try), c=0.
// mode=1: first FD of a level: 13 configs, c = e>>3 (0..12).
// mode=2: FD: 12 configs, c = (e>>3)+1 (1..12).
// ---------------------------------------------------------------------------
__global__ __launch_bounds__(256) void eval_kernel(
    const float* __restrict__ src, const float* __restrict__ tgt,
    const float* __restrict__ theta, const int* __restrict__ active,
    double* __restrict__ partials, int D, int K, float ss, int mode)
{
    int gb = blockIdx.x;
    int k = gb % K;
    int e = gb / K;          // e = c'*8 + b
    int b = e & 7;
    int c = (mode == 0) ? 0 : ((mode == 1) ? (e >> 3) : (e >> 3) + 1);
    if (!active[b]) return;

    float th[6];
#pragma unroll
    for (int j = 0; j < 6; ++j) th[j] = theta[b * 6 + j];
    if (c > 0) {
        int j = (c - 1) % 6;
        th[j] += (c <= 6) ? ss : -ss;
    }
    float R[9], t[3];
    compute_R(th, R, t);

    int logD = (D == 64) ? 6 : ((D == 32) ? 5 : 4);
    int n = D * D * D;
    int chunk = n / K;
    int vstart = k * chunk;
    float step = 2.0f / (float)(D - 1);
    float scale = (float)(D - 1) * 0.5f;
    const float* s = src + (size_t)b * n;
    const float* g = tgt + (size_t)b * n;

    double acc = 0.0;
    for (int v = vstart + threadIdx.x; v < vstart + chunk; v += 256) {
        int kk = v & (D - 1);
        int jj = (v >> logD) & (D - 1);
        int ii = v >> (2 * logD);
        float x0 = -1.0f + (float)ii * step;
        float x1 = -1.0f + (float)jj * step;
        float x2 = -1.0f + (float)kk * step;
        float p0 = R[0] * x0 + R[1] * x1 + R[2] * x2 + t[0];
        float p1 = R[3] * x0 + R[4] * x1 + R[5] * x2 + t[1];
        float p2 = R[6] * x0 + R[7] * x1 + R[8] * x2 + t[2];
        float c0 = (p0 + 1.0f) * scale;
        float c1 = (p1 + 1.0f) * scale;
        float c2 = (p2 + 1.0f) * scale;
        float w = tri_sample(s, D, c0, c1, c2);
        float d = w - g[v];
        acc += (double)(d * d);
    }

    __shared__ double red[256];
    red[threadIdx.x] = acc;
    __syncthreads();
#pragma unroll
    for (int st = 128; st > 0; st >>= 1) {
        if (threadIdx.x < st) red[threadIdx.x] += red[threadIdx.x + st];
        __syncthreads();
    }
    if (threadIdx.x == 0) partials[(size_t)(c * 8 + b) * K + k] = red[0];
}

// ---------------------------------------------------------------------------
// update1: reduce FD losses, base loss from c=0 (first) or lcur (carried),
// grad + momentum, normalized direction, theta_try.
// ---------------------------------------------------------------------------
__global__ void update1_kernel(const float* __restrict__ theta,
                               float* __restrict__ theta_try,
                               float* __restrict__ momentum,
                               float* __restrict__ lcur,
                               float* __restrict__ lall,
                               const int* __restrict__ active,
                               const double* __restrict__ partials,
                               int K, int n, float ss, int first)
{
    __shared__ float lossf[104];
    int t = threadIdx.x;
    int nslots = first ? 104 : 96;
    if (t < nslots) {
        int slot = first ? t : t + 8;     // skip c=0 slots when carried
        double s = 0.0;
        for (int i = 0; i < K; ++i) s += partials[(size_t)slot * K + i];
        lossf[slot] = (float)(s / (double)n);
    }
    __syncthreads();
    if (t < 8 && active[t]) {
        int b = t;
        float lb = first ? lossf[b] : lcur[b];
        lcur[b] = lb;
        lall[b] = lb;
        float ub[6];
#pragma unroll
        for (int j = 0; j < 6; ++j) {
            float grad = lossf[(1 + j) * 8 + b] - lossf[(7 + j) * 8 + b];
            float u = first ? grad : (momentum[b * 6 + j] * 0.1f + grad);
            momentum[b * 6 + j] = u;
            ub[j] = u;
        }
        float ss2 = 0.0f;
#pragma unroll
        for (int j = 0; j < 6; ++j) ss2 += ub[j] * ub[j];
        float denom = sqrtf(ss2) + 1e-6f;
#pragma unroll
        for (int j = 0; j < 6; ++j) {
            float d = ub[j] / denom;
            theta_try[b * 6 + j] = theta[b * 6 + j] - ss * d;
        }
    }
}

// ---------------------------------------------------------------------------
// update2: reduce loss_new, accept/reject (carrying lcur), deactivate;
// optionally reset active for the next step.
// ---------------------------------------------------------------------------
__global__ void update2_kernel(float* __restrict__ theta,
                               const float* __restrict__ theta_try,
                               float* __restrict__ lcur,
                               int* __restrict__ active,
                               const double* __restrict__ partials,
                               int K, int n, int reset)
{
    int b = threadIdx.x;
    if (b < 8) {
        if (active[b]) {
            double s = 0.0;
            for (int i = 0; i < K; ++i) s += partials[(size_t)b * K + i];
            float ln = (float)(s / (double)n);
            if (ln + 1e-4f < lcur[b]) {
#pragma unroll
                for (int j = 0; j < 6; ++j) theta[b * 6 + j] = theta_try[b * 6 + j];
                lcur[b] = ln;
            } else {
                active[b] = 0;
            }
        }
        if (reset) active[b] = 1;
    }
}

// ---------------------------------------------------------------------------
// Pool both src and tgt in one kernel: mean over f^3 blocks (input D=64).
// ---------------------------------------------------------------------------
__global__ void pool_kernel(const float* __restrict__ a, const float* __restrict__ bsrc,
                            float* __restrict__ oa, float* __restrict__ ob, int f)
{
    int Do = 64 / f;
    int n = 8 * Do * Do * Do;
    int idx = blockIdx.x * blockDim.x + threadIdx.x;
    if (idx >= 2 * n) return;
    const float* in = (idx < n) ? a : bsrc;
    float* out = (idx < n) ? oa : ob;
    int id = (idx < n) ? idx : idx - n;
    int kk = id % Do;
    int jj = (id / Do) % Do;
    int ii = (id / (Do * Do)) % Do;
    int bq = id / (Do * Do * Do);
    const float* v = in + (size_t)bq * 64 * 64 * 64;
    double s = 0.0;
    for (int p = 0; p < f; ++p)
        for (int q = 0; q < f; ++q)
            for (int r = 0; r < f; ++r)
                s += (double)v[((ii * f + p) * 64 + (jj * f + q)) * 64 + (kk * f + r)];
    out[id] = (float)(s / (double)(f * f * f));
}

__global__ void init_kernel(const float* __restrict__ theta_in,
                            float* __restrict__ theta_deg,
                            int* __restrict__ active)
{
    int t = threadIdx.x;
    if (t < 48) {
        int j = t % 6;
        float d2r = (j < 3) ? PI180F : 1.0f;
        theta_deg[t] = theta_in[t] / d2r;
    }
    if (t < 8) active[t] = 1;
}

__global__ void finalize_kernel(const float* __restrict__ theta0,
                                const float* __restrict__ theta_deg,
                                const float* __restrict__ loss_all,
                                float* __restrict__ out)
{
    int t = threadIdx.x;
    if (t < 48) {
        int j = t % 6;
        float d2r = (j < 3) ? PI180F : 1.0f;
        float td = theta_deg[t] * d2r;
        float dt = td - theta0[t];
        out[t] = theta0[t] + dt;
    } else if (t < 56) {
        out[t] = loss_all[t - 48];
    }
}

// ---------------------------------------------------------------------------
extern "C" void kernel_launch(void* const* d_in, const int* in_sizes, int n_in,
                              void* d_out, int out_size, void* d_ws, size_t ws_size,
                              hipStream_t stream)
{
    const float* theta0 = (const float*)d_in[0];
    const float* source = (const float*)d_in[1];
    const float* target = (const float*)d_in[2];
    float* out = (float*)d_out;

    char* ws = (char*)d_ws;
    size_t off = 0;
    auto alloc = [&](size_t bytes) -> void* {
        off = (off + 255) & ~(size_t)255;
        void* p = ws + off;
        off += bytes;
        return p;
    };
    float*  theta  = (float*)alloc(48 * 4);
    float*  ttry   = (float*)alloc(48 * 4);
    float*  mom    = (float*)alloc(48 * 4);
    float*  lcur   = (float*)alloc(8 * 4);
    float*  lall   = (float*)alloc(8 * 4);
    int*    active = (int*)alloc(8 * 4);
    double* pA     = (double*)alloc(104 * 32 * 8);
    double* pB     = (double*)alloc(8 * 128 * 8);
    float*  src2   = (float*)alloc((size_t)8 * 32768 * 4);
    float*  tgt2   = (float*)alloc((size_t)8 * 32768 * 4);
    float*  src4   = (float*)alloc((size_t)8 * 4096 * 4);
    float*  tgt4   = (float*)alloc((size_t)8 * 4096 * 4);

    pool_kernel<<<(2 * 8 * 32768 + 255) / 256, 256, 0, stream>>>(source, target, src2, tgt2, 2);
    pool_kernel<<<(2 * 8 * 4096 + 255) / 256, 256, 0, stream>>>(source, target, src4, tgt4, 4);
    init_kernel<<<1, 64, 0, stream>>>(theta0, theta, active);

    struct Lv { const float* s; const float* g; int D; int K; int K3; float ss0; };
    Lv lvs[3] = {
        { src4,   tgt4,   16,  2,   8,  8.0f },
        { src2,   tgt2,   32,  8,  32,  4.0f },
        { source, target, 64, 32, 128,  2.0f },
    };

    for (int L = 0; L < 3; ++L) {
        Lv lv = lvs[L];
        int n = lv.D * lv.D * lv.D;
        float ssv = lv.ss0;
        for (int s = 0; s < 4; ++s) {
            for (int it = 0; it < 10; ++it) {
                int first = (s == 0 && it == 0) ? 1 : 0;
                int nconf = first ? 13 : 12;
                eval_kernel<<<nconf * 8 * lv.K, 256, 0, stream>>>(
                    lv.s, lv.g, theta, active, pA, lv.D, lv.K, ssv, first ? 1 : 2);
                update1_kernel<<<1, 128, 0, stream>>>(
                    theta, ttry, mom, lcur, lall, active, pA, lv.K, n, ssv, first);
                eval_kernel<<<8 * lv.K3, 256, 0, stream>>>(
                    lv.s, lv.g, ttry, active, pB, lv.D, lv.K3, 0.0f, 0);
                update2_kernel<<<1, 64, 0, stream>>>(
                    theta, ttry, lcur, active, pB, lv.K3, n, (it == 9) ? 1 : 0);
            }
            ssv *= 0.5f;
        }
    }

    finalize_kernel<<<1, 64, 0, stream>>>(theta0, theta, lall, out);
}

// Round 4
// 1384.999 us; speedup vs baseline: 6.4561x; 1.1054x over previous
//
#include <hip/hip_runtime.h>

// np.float32(np.pi / 180)
#define PI180F 0.017453292519943295f

// ---------------------------------------------------------------------------
// Rotation matrix, matching the reference's (Rz @ Ry) @ Rx in fp32.
// ---------------------------------------------------------------------------
__device__ __forceinline__ void compute_R(const float th[6], float R[9], float t[3]) {
    float ax = th[0] * PI180F, ay = th[1] * PI180F, az = th[2] * PI180F;
    float cx = cosf(ax), sx = sinf(ax);
    float cy = cosf(ay), sy = sinf(ay);
    float cz = cosf(az), sz = sinf(az);
    R[0] = cz * cy;  R[1] = (cz * sy) * sx - sz * cx;  R[2] = (cz * sy) * cx + sz * sx;
    R[3] = sz * cy;  R[4] = (sz * sy) * sx + cz * cx;  R[5] = (sz * sy) * cx - cz * sx;
    R[6] = -sy;      R[7] = cy * sx;                   R[8] = cy * cx;
    t[0] = th[3]; t[1] = th[4]; t[2] = th[5];
}

// ---------------------------------------------------------------------------
// Trilinear sample on a zero-padded volume (side P=D+3: zeros at plane 0 and
// planes D+1, D+2; data at 1..D). Bit-identical fp32 results to the
// predicated form: identical weights, identical accumulation order; border /
// OOB corners load literal 0.0f instead of being selected to 0.
// ---------------------------------------------------------------------------
template<int D>
__device__ __forceinline__ float tri_sample_pad(const float* __restrict__ vol,
                                                float c0, float c1, float c2) {
    constexpr int P = D + 3;
    float f0 = floorf(c0), f1 = floorf(c1), f2 = floorf(c2);
    int i0 = (int)f0, i1 = (int)f1, i2 = (int)f2;
    float t0 = c0 - f0, t1 = c1 - f1, t2 = c2 - f2;
    float w0[2] = {1.0f - t0, t0};
    float w1[2] = {1.0f - t1, t1};
    float w2[2] = {1.0f - t2, t2};
    // i in [-1, D-1]  ->  padded index i+1 (covers partial-validity borders);
    // otherwise sentinel D+1 so both corner planes (D+1, D+2) are zero.
    int ip0 = ((unsigned)(i0 + 1) <= (unsigned)D) ? (i0 + 1) : (D + 1);
    int ip1 = ((unsigned)(i1 + 1) <= (unsigned)D) ? (i1 + 1) : (D + 1);
    int ip2 = ((unsigned)(i2 + 1) <= (unsigned)D) ? (i2 + 1) : (D + 1);
    const float* p = vol + ((ip0 * P + ip1) * P + ip2);
    float acc = 0.0f;
    acc += ((w0[0] * w1[0]) * w2[0]) * p[0];
    acc += ((w0[0] * w1[0]) * w2[1]) * p[1];
    acc += ((w0[0] * w1[1]) * w2[0]) * p[P];
    acc += ((w0[0] * w1[1]) * w2[1]) * p[P + 1];
    acc += ((w0[1] * w1[0]) * w2[0]) * p[P * P];
    acc += ((w0[1] * w1[0]) * w2[1]) * p[P * P + 1];
    acc += ((w0[1] * w1[1]) * w2[0]) * p[P * P + P];
    acc += ((w0[1] * w1[1]) * w2[1]) * p[P * P + P + 1];
    return acc;
}

// ---------------------------------------------------------------------------
// Eval kernel (round-3 structure, templated on D, padded src):
// mode=0: trial (1 config, theta ptr = theta_try), c=0.
// mode=1: first FD of a level: 13 configs, c = e>>3 (0..12).
// mode=2: FD: 12 configs, c = (e>>3)+1 (1..12).
// ---------------------------------------------------------------------------
template<int D>
__global__ __launch_bounds__(256) void eval_kernel(
    const float* __restrict__ srcp, const float* __restrict__ tgt,
    const float* __restrict__ theta, const int* __restrict__ active,
    double* __restrict__ partials, int K, float ss, int mode)
{
    constexpr int logD = (D == 64) ? 6 : ((D == 32) ? 5 : 4);
    constexpr int n = D * D * D;
    constexpr int PS = (D + 3) * (D + 3) * (D + 3);
    int gb = blockIdx.x;
    int k = gb % K;
    int e = gb / K;          // e = c'*8 + b
    int b = e & 7;
    int c = (mode == 0) ? 0 : ((mode == 1) ? (e >> 3) : (e >> 3) + 1);
    if (!active[b]) return;

    float th[6];
#pragma unroll
    for (int j = 0; j < 6; ++j) th[j] = theta[b * 6 + j];
    if (c > 0) {
        int j = (c - 1) % 6;
        th[j] += (c <= 6) ? ss : -ss;
    }
    float R[9], t[3];
    compute_R(th, R, t);

    const int chunk = n / K;
    const int vstart = k * chunk;
    const float step = 2.0f / (float)(D - 1);
    const float scale = (float)(D - 1) * 0.5f;
    const float* s = srcp + (size_t)b * PS;
    const float* g = tgt + (size_t)b * n;

    double acc = 0.0;
    for (int v = vstart + threadIdx.x; v < vstart + chunk; v += 256) {
        int kk = v & (D - 1);
        int jj = (v >> logD) & (D - 1);
        int ii = v >> (2 * logD);
        float x0 = -1.0f + (float)ii * step;
        float x1 = -1.0f + (float)jj * step;
        float x2 = -1.0f + (float)kk * step;
        float p0 = R[0] * x0 + R[1] * x1 + R[2] * x2 + t[0];
        float p1 = R[3] * x0 + R[4] * x1 + R[5] * x2 + t[1];
        float p2 = R[6] * x0 + R[7] * x1 + R[8] * x2 + t[2];
        float c0 = (p0 + 1.0f) * scale;
        float c1 = (p1 + 1.0f) * scale;
        float c2 = (p2 + 1.0f) * scale;
        float w = tri_sample_pad<D>(s, c0, c1, c2);
        float d = w - g[v];
        acc += (double)(d * d);
    }

    __shared__ double red[256];
    red[threadIdx.x] = acc;
    __syncthreads();
#pragma unroll
    for (int st = 128; st > 0; st >>= 1) {
        if (threadIdx.x < st) red[threadIdx.x] += red[threadIdx.x + st];
        __syncthreads();
    }
    if (threadIdx.x == 0) partials[(size_t)(c * 8 + b) * K + k] = red[0];
}

// ---------------------------------------------------------------------------
// update1: reduce FD losses, base loss from c=0 (first) or lcur (carried),
// grad + momentum, normalized direction, theta_try.
// ---------------------------------------------------------------------------
__global__ void update1_kernel(const float* __restrict__ theta,
                               float* __restrict__ theta_try,
                               float* __restrict__ momentum,
                               float* __restrict__ lcur,
                               float* __restrict__ lall,
                               const int* __restrict__ active,
                               const double* __restrict__ partials,
                               int K, int n, float ss, int first)
{
    __shared__ float lossf[104];
    int t = threadIdx.x;
    int nslots = first ? 104 : 96;
    if (t < nslots) {
        int slot = first ? t : t + 8;     // skip c=0 slots when carried
        double s = 0.0;
        for (int i = 0; i < K; ++i) s += partials[(size_t)slot * K + i];
        lossf[slot] = (float)(s / (double)n);
    }
    __syncthreads();
    if (t < 8 && active[t]) {
        int b = t;
        float lb = first ? lossf[b] : lcur[b];
        lcur[b] = lb;
        lall[b] = lb;
        float ub[6];
#pragma unroll
        for (int j = 0; j < 6; ++j) {
            float grad = lossf[(1 + j) * 8 + b] - lossf[(7 + j) * 8 + b];
            float u = first ? grad : (momentum[b * 6 + j] * 0.1f + grad);
            momentum[b * 6 + j] = u;
            ub[j] = u;
        }
        float ss2 = 0.0f;
#pragma unroll
        for (int j = 0; j < 6; ++j) ss2 += ub[j] * ub[j];
        float denom = sqrtf(ss2) + 1e-6f;
#pragma unroll
        for (int j = 0; j < 6; ++j) {
            float d = ub[j] / denom;
            theta_try[b * 6 + j] = theta[b * 6 + j] - ss * d;
        }
    }
}

// ---------------------------------------------------------------------------
// update2: reduce loss_new, accept/reject (carrying lcur), deactivate;
// optionally reset active for the next step.
// ---------------------------------------------------------------------------
__global__ void update2_kernel(float* __restrict__ theta,
                               const float* __restrict__ theta_try,
                               float* __restrict__ lcur,
                               int* __restrict__ active,
                               const double* __restrict__ partials,
                               int K, int n, int reset)
{
    int b = threadIdx.x;
    if (b < 8) {
        if (active[b]) {
            double s = 0.0;
            for (int i = 0; i < K; ++i) s += partials[(size_t)b * K + i];
            float ln = (float)(s / (double)n);
            if (ln + 1e-4f < lcur[b]) {
#pragma unroll
                for (int j = 0; j < 6; ++j) theta[b * 6 + j] = theta_try[b * 6 + j];
                lcur[b] = ln;
            } else {
                active[b] = 0;
            }
        }
        if (reset) active[b] = 1;
    }
}

// ---------------------------------------------------------------------------
// Pool: mean over f^3 blocks; src-pool written into padded layout, tgt-pool
// linear. Accumulation order identical to round 3.
// ---------------------------------------------------------------------------
template<int f>
__global__ void pool_pad_kernel(const float* __restrict__ src, const float* __restrict__ tgt,
                                float* __restrict__ srcp, float* __restrict__ tgtp)
{
    constexpr int Do = 64 / f;
    constexpr int P = Do + 3;
    constexpr int n = 8 * Do * Do * Do;
    int idx = blockIdx.x * blockDim.x + threadIdx.x;
    if (idx >= 2 * n) return;
    bool is_src = idx < n;
    int id = is_src ? idx : idx - n;
    int kk = id % Do;
    int jj = (id / Do) % Do;
    int ii = (id / (Do * Do)) % Do;
    int b  = id / (Do * Do * Do);
    const float* v = (is_src ? src : tgt) + (size_t)b * 262144;
    double s = 0.0;
    for (int p = 0; p < f; ++p)
        for (int q = 0; q < f; ++q)
            for (int r = 0; r < f; ++r)
                s += (double)v[((ii * f + p) * 64 + (jj * f + q)) * 64 + (kk * f + r)];
    float val = (float)(s / (double)(f * f * f));
    if (is_src) srcp[(size_t)b * P * P * P + (((ii + 1) * P + (jj + 1)) * P + (kk + 1))] = val;
    else        tgtp[id] = val;
}

// Copy D=64 src into padded layout (P=67).
__global__ void pad_copy_kernel(const float* __restrict__ src, float* __restrict__ dst)
{
    int idx = blockIdx.x * blockDim.x + threadIdx.x;
    if (idx >= 8 * 262144) return;
    int kk = idx & 63;
    int jj = (idx >> 6) & 63;
    int ii = (idx >> 12) & 63;
    int b  = idx >> 18;
    dst[(size_t)b * 67 * 67 * 67 + (((ii + 1) * 67 + (jj + 1)) * 67 + (kk + 1))] = src[idx];
}

__global__ void init_kernel(const float* __restrict__ theta_in,
                            float* __restrict__ theta_deg,
                            int* __restrict__ active)
{
    int t = threadIdx.x;
    if (t < 48) {
        int j = t % 6;
        float d2r = (j < 3) ? PI180F : 1.0f;
        theta_deg[t] = theta_in[t] / d2r;
    }
    if (t < 8) active[t] = 1;
}

__global__ void finalize_kernel(const float* __restrict__ theta0,
                                const float* __restrict__ theta_deg,
                                const float* __restrict__ loss_all,
                                float* __restrict__ out)
{
    int t = threadIdx.x;
    if (t < 48) {
        int j = t % 6;
        float d2r = (j < 3) ? PI180F : 1.0f;
        float td = theta_deg[t] * d2r;
        float dt = td - theta0[t];
        out[t] = theta0[t] + dt;
    } else if (t < 56) {
        out[t] = loss_all[t - 48];
    }
}

// ---------------------------------------------------------------------------
template<int D>
static void run_level(const float* srcp, const float* tgt,
                      float* theta, float* ttry, float* mom,
                      float* lcur, float* lall, int* active,
                      double* pA, double* pB, int K, int K3, float ss0,
                      hipStream_t stream)
{
    constexpr int n = D * D * D;
    float ssv = ss0;
    for (int s = 0; s < 4; ++s) {
        for (int it = 0; it < 10; ++it) {
            int first = (s == 0 && it == 0) ? 1 : 0;
            int nconf = first ? 13 : 12;
            eval_kernel<D><<<nconf * 8 * K, 256, 0, stream>>>(
                srcp, tgt, theta, active, pA, K, ssv, first ? 1 : 2);
            update1_kernel<<<1, 128, 0, stream>>>(
                theta, ttry, mom, lcur, lall, active, pA, K, n, ssv, first);
            eval_kernel<D><<<8 * K3, 256, 0, stream>>>(
                srcp, tgt, ttry, active, pB, K3, 0.0f, 0);
            update2_kernel<<<1, 64, 0, stream>>>(
                theta, ttry, lcur, active, pB, K3, n, (it == 9) ? 1 : 0);
        }
        ssv *= 0.5f;
    }
}

extern "C" void kernel_launch(void* const* d_in, const int* in_sizes, int n_in,
                              void* d_out, int out_size, void* d_ws, size_t ws_size,
                              hipStream_t stream)
{
    const float* theta0 = (const float*)d_in[0];
    const float* source = (const float*)d_in[1];
    const float* target = (const float*)d_in[2];
    float* out = (float*)d_out;

    char* ws = (char*)d_ws;
    size_t off = 0;
    auto alloc = [&](size_t bytes) -> void* {
        off = (off + 255) & ~(size_t)255;
        void* p = ws + off;
        off += bytes;
        return p;
    };
    float*  theta  = (float*)alloc(48 * 4);
    float*  ttry   = (float*)alloc(48 * 4);
    float*  mom    = (float*)alloc(48 * 4);
    float*  lcur   = (float*)alloc(8 * 4);
    float*  lall   = (float*)alloc(8 * 4);
    int*    active = (int*)alloc(8 * 4);
    double* pA     = (double*)alloc(104 * 32 * 8);
    double* pB     = (double*)alloc(8 * 128 * 8);
    float*  tgt2   = (float*)alloc((size_t)8 * 32768 * 4);
    float*  tgt4   = (float*)alloc((size_t)8 * 4096 * 4);
    const size_t PS16 = 19 * 19 * 19, PS32 = 35 * 35 * 35, PS64 = 67 * 67 * 67;
    float*  pad16  = (float*)alloc((size_t)8 * PS16 * 4);
    float*  pad32  = (float*)alloc((size_t)8 * PS32 * 4);
    float*  pad64  = (float*)alloc((size_t)8 * PS64 * 4);

    hipMemsetAsync(pad16, 0, (size_t)8 * PS16 * 4, stream);
    hipMemsetAsync(pad32, 0, (size_t)8 * PS32 * 4, stream);
    hipMemsetAsync(pad64, 0, (size_t)8 * PS64 * 4, stream);

    pool_pad_kernel<2><<<(2 * 8 * 32768 + 255) / 256, 256, 0, stream>>>(source, target, pad32, tgt2);
    pool_pad_kernel<4><<<(2 * 8 * 4096 + 255) / 256, 256, 0, stream>>>(source, target, pad16, tgt4);
    pad_copy_kernel<<<(8 * 262144 + 255) / 256, 256, 0, stream>>>(source, pad64);
    init_kernel<<<1, 64, 0, stream>>>(theta0, theta, active);

    run_level<16>(pad16, tgt4, theta, ttry, mom, lcur, lall, active, pA, pB,  2,   8, 8.0f, stream);
    run_level<32>(pad32, tgt2, theta, ttry, mom, lcur, lall, active, pA, pB,  8,  32, 4.0f, stream);
    run_level<64>(pad64, target, theta, ttry, mom, lcur, lall, active, pA, pB, 32, 128, 2.0f, stream);

    finalize_kernel<<<1, 64, 0, stream>>>(theta0, theta, lall, out);
}